// Round 9
// baseline (141.604 us; speedup 1.0000x reference)
//
#include <hip/hip_runtime.h>
#include <hip/hip_bf16.h>
#include <stdint.h>

#define TOKENS 2048
#define DD 1024
#define HH 2048
#define NE 8
#define RP_CAP 3072   // padded-row capacity
#define BM 64
#define BN 64
#define BK 64

typedef float f32x4 __attribute__((ext_vector_type(4)));
typedef short bf16x8 __attribute__((ext_vector_type(8)));
typedef unsigned int u32;

__device__ __forceinline__ unsigned short f2bf(float f) {
    union { float f; u32 u; } v; v.f = f;
    u32 u = v.u;
    return (unsigned short)((u + 0x7fffu + ((u >> 16) & 1u)) >> 16);
}

// ---------------- routing: expert per token, padded segments (64-aligned), perm ----------------
__global__ __launch_bounds__(256) void k_route(const int* __restrict__ orig,
                                               const int* __restrict__ hmap,
                                               int* __restrict__ hdr) {
    __shared__ int s_e[TOKENS];
    __shared__ int s_cnt[NE];
    __shared__ int s_off[NE];
    int tid = threadIdx.x;
    if (tid < NE) s_cnt[tid] = 0;
    __syncthreads();
    for (int t = tid; t < TOKENS; t += 256) {
        int e = hmap[orig[t]];
        s_e[t] = e;
        atomicAdd(&s_cnt[e], 1);
    }
    __syncthreads();
    if (tid == 0) {
        int run = 0;
        for (int e = 0; e < NE; ++e) {
            s_off[e] = run;
            hdr[e] = s_cnt[e];
            hdr[8 + e] = run;
            run += ((s_cnt[e] + BM - 1) / BM) * BM;
        }
        hdr[16] = run;
    }
    __syncthreads();
    int* perm = hdr + 64;
    for (int r = tid; r < RP_CAP; r += 256) perm[r] = -1;
    if (tid < NE) s_cnt[tid] = 0;
    __syncthreads();
    for (int t = tid; t < TOKENS; t += 256) {
        int e = s_e[t];
        int pos = s_off[e] + atomicAdd(&s_cnt[e], 1);
        perm[pos] = t;
    }
}

// ---------------- gather x -> bf16 permuted padded layout ----------------
__global__ __launch_bounds__(256) void k_gather(const float* __restrict__ x,
                                                const int* __restrict__ hdr,
                                                unsigned short* __restrict__ xp) {
    int r = blockIdx.x;
    int t = hdr[64 + r];  // perm
    int tid = threadIdx.x;
    ushort4* dst = (ushort4*)(xp + (size_t)r * DD);
    if (t >= 0) {
        const float4* src = (const float4*)(x + (size_t)t * DD);
        float4 v = src[tid];
        ushort4 o;
        o.x = f2bf(v.x); o.y = f2bf(v.y); o.z = f2bf(v.z); o.w = f2bf(v.w);
        dst[tid] = o;
    } else {
        ushort4 z; z.x = 0; z.y = 0; z.z = 0; z.w = 0;
        dst[tid] = z;
    }
}

// ---------------- grouped GEMM: C = A(bf16,[RP][K]) * W(f32,[NE][N][K])^T ----------------
// 256 threads, 4 waves (2M x 2N, 32x32 per wave), tile 64x64, BK=64.
// ALL staging via global_load_lds (A bf16, B raw f32 -> converted in COMPUTE).
// Ring-3 LDS, prefetch distance 2, counted drain:
//   step t: STAGE(t+2) -> ring[(t+2)%3] (6 gload_lds/thread);
//           COMPUTE(ring[t%3]); s_waitcnt vmcnt(6) lgkmcnt(0)  [drains stage(t+1),
//           keeps stage(t+2) in flight]; s_barrier.
// Safety: buf read at t was staged at t-2 and drained at end of t-1 + barrier.
// Buf overwritten at t (stage t+2) had its last readers at step t-1, which
// completed their ds_reads before the t-1 -> t barrier. No kept-load is ever
// consumed before a drain that covers it.
template<int KDIM, int NDIM, bool L2EPI>
__global__ __launch_bounds__(256, 2) void k_gemm(const unsigned short* __restrict__ A,
                                                 const float* __restrict__ W,
                                                 const float* __restrict__ bias,
                                                 const int* __restrict__ hdr,
                                                 unsigned short* __restrict__ hout,
                                                 float* __restrict__ out) {
    int total = hdr[16];
    int row0 = blockIdx.y * BM;
    if (row0 >= total) return;
    int e = 0;
#pragma unroll
    for (int i = 1; i < NE; ++i)
        if (row0 >= hdr[8 + i]) e = i;

    int n0 = blockIdx.x * BN;
    const float* We = W + (size_t)e * NDIM * KDIM;
    const float* be = bias + (size_t)e * NDIM;

    constexpr int ASZ = BM * BK;       // bf16 elems per A buf (8 KB)
    constexpr int BSZ = BN * BK;       // f32 elems per B buf (16 KB)
    __shared__ __align__(16) unsigned short As[3 * ASZ];  // 24 KB
    __shared__ __align__(16) float          Bs[3 * BSZ];  // 48 KB

    int tid = threadIdx.x;
    int w = tid >> 6, lane = tid & 63;
    int wr = w >> 1, wc = w & 1;          // wave grid 2M x 2N (32x32 per wave)
    int fr = lane & 15, hi = lane >> 4;

    f32x4 acc[2][2];
#pragma unroll
    for (int m = 0; m < 2; ++m)
#pragma unroll
        for (int n = 0; n < 2; ++n) acc[m][n] = f32x4{0.f, 0.f, 0.f, 0.f};

    // ---- STAGE: 2 A gload_lds (bf16, 8-elem slots, XOR row&7) +
    //             4 B gload_lds (f32, 4-elem slots, XOR row&15). Linear LDS dest,
    //             inverse-swizzled global source (both-sides rule).
    auto STAGE = [&](int aoff, int boff, int k0) {
#pragma unroll
        for (int j = 0; j < 2; ++j) {
            int c = j * 256 + tid;          // 16B chunk id in [0,512)
            int row = c >> 3;               // [0,64)
            int slot = c & 7;
            int gslot = slot ^ (row & 7);
            const unsigned short* gp = A + (size_t)(row0 + row) * KDIM + k0 + gslot * 8;
            unsigned short* lp = (unsigned short*)As + aoff + j * 2048 + w * 512;  // wave-uniform
            __builtin_amdgcn_global_load_lds((const __attribute__((address_space(1))) u32*)gp,
                                             (__attribute__((address_space(3))) u32*)lp, 16, 0, 0);
        }
#pragma unroll
        for (int j = 0; j < 4; ++j) {
            int c = j * 256 + tid;          // 16B chunk id in [0,1024)
            int row = c >> 4;               // [0,64)
            int slot = c & 15;
            int gslot = slot ^ (row & 15);
            const float* gp = We + (size_t)(n0 + row) * KDIM + k0 + gslot * 4;
            float* lp = Bs + boff + j * 1024 + w * 256;                            // wave-uniform
            __builtin_amdgcn_global_load_lds((const __attribute__((address_space(1))) u32*)gp,
                                             (__attribute__((address_space(3))) u32*)lp, 16, 0, 0);
        }
    };
    auto COMPUTE = [&](int aoff, int boff) {
        const unsigned short* Ab = As + aoff;
        const float* Bb = Bs + boff;
#pragma unroll
        for (int kk = 0; kk < BK; kk += 32) {
            bf16x8 af[2], bfr[2];
#pragma unroll
            for (int m = 0; m < 2; ++m) {
                int rr = wr * 32 + m * 16 + fr;
                int idx = (rr * 64 + kk + hi * 8) ^ ((rr & 7) << 3);
                af[m] = *(const bf16x8*)&Ab[idx];
            }
#pragma unroll
            for (int n = 0; n < 2; ++n) {
                int cn = wc * 32 + n * 16 + fr;
                int s0 = (kk + hi * 8) >> 2;          // even 4-f32 slot
                int xr = cn & 15;
                const f32x4 v0 = *(const f32x4*)&Bb[cn * 64 + ((s0)     ^ xr) * 4];
                const f32x4 v1 = *(const f32x4*)&Bb[cn * 64 + ((s0 + 1) ^ xr) * 4];
                union { bf16x8 v; unsigned short s[8]; } o;
                o.s[0] = f2bf(v0[0]); o.s[1] = f2bf(v0[1]); o.s[2] = f2bf(v0[2]); o.s[3] = f2bf(v0[3]);
                o.s[4] = f2bf(v1[0]); o.s[5] = f2bf(v1[1]); o.s[6] = f2bf(v1[2]); o.s[7] = f2bf(v1[3]);
                bfr[n] = o.v;
            }
#pragma unroll
            for (int m = 0; m < 2; ++m)
#pragma unroll
                for (int n = 0; n < 2; ++n)
                    acc[m][n] = __builtin_amdgcn_mfma_f32_16x16x32_bf16(af[m], bfr[n], acc[m][n], 0, 0, 0);
        }
    };

    constexpr int NT = KDIM / BK;   // 16 or 32

#define WAIT6   do { asm volatile("s_waitcnt vmcnt(6) lgkmcnt(0)" ::: "memory"); \
                     __builtin_amdgcn_sched_barrier(0); } while (0)
#define WAIT0   do { asm volatile("s_waitcnt vmcnt(0) lgkmcnt(0)" ::: "memory"); \
                     __builtin_amdgcn_sched_barrier(0); } while (0)
#define BARRIER do { __builtin_amdgcn_s_barrier(); asm volatile("" ::: "memory"); } while (0)

    int a0 = 0, a1 = ASZ, a2 = 2 * ASZ;
    int b0 = 0, b1 = BSZ, b2 = 2 * BSZ;

    // prologue: stage tiles 0 and 1
    STAGE(a0, b0, 0);
    STAGE(a1, b1, BK);
    WAIT6;            // drain stage(0); keep stage(1) in flight
    BARRIER;

    for (int t = 0; t < NT; ++t) {
        if (t + 2 < NT) STAGE(a2, b2, (t + 2) * BK);   // wave-uniform guard
        COMPUTE(a0, b0);
        if (t + 2 < NT)      { WAIT6; BARRIER; }       // drain stage(t+1), keep stage(t+2)
        else if (t + 1 < NT) { WAIT0; BARRIER; }       // tail: full drain before last tile
        // rotate ring: (0,1,2) <- (1,2,0)
        int ta = a0; a0 = a1; a1 = a2; a2 = ta;
        int tb = b0; b0 = b1; b1 = b2; b2 = tb;
    }
#undef WAIT6
#undef WAIT0
#undef BARRIER

    // ---- epilogue ----
    const int* perm = hdr + 64;
    int rbase = row0 + wr * 32 + hi * 4;
    int cbase = n0 + wc * 32 + fr;
    if constexpr (!L2EPI) {
#pragma unroll
        for (int n = 0; n < 2; ++n) {
            int cg = cbase + n * 16;
            float bvv = be[cg];
#pragma unroll
            for (int m = 0; m < 2; ++m) {
                int rg = rbase + m * 16;
#pragma unroll
                for (int r = 0; r < 4; ++r) {
                    float v = acc[m][n][r] + bvv;
                    v = v > 0.f ? v : 0.f;
                    hout[(size_t)(rg + r) * NDIM + cg] = f2bf(v);
                }
            }
        }
    } else {
        float bvv[2];
#pragma unroll
        for (int n = 0; n < 2; ++n) bvv[n] = be[cbase + n * 16];
#pragma unroll
        for (int m = 0; m < 2; ++m) {
            int rg = rbase + m * 16;
#pragma unroll
            for (int r = 0; r < 4; ++r) {
                int tk = perm[rg + r];
                if (tk < 0) continue;
                float* op = out + (size_t)tk * DD;
#pragma unroll
                for (int n = 0; n < 2; ++n)
                    op[cbase + n * 16] = acc[m][n][r] + bvv[n];
            }
        }
    }
}

extern "C" void kernel_launch(void* const* d_in, const int* in_sizes, int n_in,
                              void* d_out, int out_size, void* d_ws, size_t ws_size,
                              hipStream_t stream) {
    const float* x    = (const float*)d_in[0];
    const int*   orig = (const int*)d_in[1];
    const int*   hmap = (const int*)d_in[2];
    const float* W1   = (const float*)d_in[3];
    const float* b1   = (const float*)d_in[4];
    const float* W2   = (const float*)d_in[5];
    const float* b2   = (const float*)d_in[6];
    float* out = (float*)d_out;

    int* hdr = (int*)d_ws;
    unsigned short* xp   = (unsigned short*)((char*)d_ws + 16384);
    unsigned short* hbuf = (unsigned short*)((char*)d_ws + 16384 + (size_t)RP_CAP * DD * 2);

    k_route<<<1, 256, 0, stream>>>(orig, hmap, hdr);
    k_gather<<<RP_CAP, 256, 0, stream>>>(x, hdr, xp);
    // grid = (n-blocks, row-blocks): same-weight-panel row-blocks share an XCD (idx%8)
    k_gemm<DD, HH, false><<<dim3(HH / BN, RP_CAP / BM), 256, 0, stream>>>(xp, W1, b1, hdr, hbuf, nullptr);
    k_gemm<HH, DD, true><<<dim3(DD / BN, RP_CAP / BM), 256, 0, stream>>>(hbuf, W2, b2, hdr, nullptr, out);
}

// Round 10
// 117.733 us; speedup vs baseline: 1.2028x; 1.2028x over previous
//
#include <hip/hip_runtime.h>
#include <hip/hip_bf16.h>
#include <stdint.h>

#define TOKENS 2048
#define DD 1024
#define HH 2048
#define NE 8
#define PAD 64
#define RP_CAP 2560   // 2048 + 8*63 rounded up to 64

typedef float f32x4 __attribute__((ext_vector_type(4)));
typedef short bf16x8 __attribute__((ext_vector_type(8)));
typedef unsigned int u32;

__device__ __forceinline__ unsigned short f2bf(float f) {
    union { float f; u32 u; } v; v.f = f;
    u32 u = v.u;
    return (unsigned short)((u + 0x7fffu + ((u >> 16) & 1u)) >> 16);
}

// ---------------- routing: expert per token, padded segments (64-aligned), perm ----------------
__global__ __launch_bounds__(256) void k_route(const int* __restrict__ orig,
                                               const int* __restrict__ hmap,
                                               int* __restrict__ hdr) {
    __shared__ int s_e[TOKENS];
    __shared__ int s_cnt[NE];
    __shared__ int s_off[NE];
    int tid = threadIdx.x;
    if (tid < NE) s_cnt[tid] = 0;
    __syncthreads();
    for (int t = tid; t < TOKENS; t += 256) {
        int e = hmap[orig[t]];
        s_e[t] = e;
        atomicAdd(&s_cnt[e], 1);
    }
    __syncthreads();
    if (tid == 0) {
        int run = 0;
        for (int e = 0; e < NE; ++e) {
            s_off[e] = run;
            hdr[e] = s_cnt[e];
            hdr[8 + e] = run;
            run += ((s_cnt[e] + PAD - 1) / PAD) * PAD;
        }
        hdr[16] = run;
    }
    __syncthreads();
    int* perm = hdr + 64;
    for (int r = tid; r < RP_CAP; r += 256) perm[r] = -1;
    if (tid < NE) s_cnt[tid] = 0;
    __syncthreads();
    for (int t = tid; t < TOKENS; t += 256) {
        int e = s_e[t];
        int pos = s_off[e] + atomicAdd(&s_cnt[e], 1);
        perm[pos] = t;
    }
}

// ---------------- gather x -> bf16 permuted padded layout ----------------
__global__ __launch_bounds__(256) void k_gather(const float* __restrict__ x,
                                                const int* __restrict__ hdr,
                                                unsigned short* __restrict__ xp) {
    int r = blockIdx.x;
    int t = hdr[64 + r];  // perm
    int tid = threadIdx.x;
    ushort4* dst = (ushort4*)(xp + (size_t)r * DD);
    if (t >= 0) {
        const float4* src = (const float4*)(x + (size_t)t * DD);
        float4 v = src[tid];
        ushort4 o;
        o.x = f2bf(v.x); o.y = f2bf(v.y); o.z = f2bf(v.z); o.w = f2bf(v.w);
        dst[tid] = o;
    } else {
        ushort4 z; z.x = 0; z.y = 0; z.z = 0; z.w = 0;
        dst[tid] = z;
    }
}

// ---------------- grouped GEMM, weight-streaming (barrier-free weight path) ----------------
// Block = 64 token-rows x 64 weight-cols; 4 waves, each owns 16 cols.
// Tokens: staged to LDS per 256-K-chunk (plain per-lane swizzled stores, 2 syncs/chunk).
// Weights: global -> registers as MFMA B-fragments, cvt_pk to bf16, NO LDS, NO barriers.
// C[token i][col j]: A-operand = token frags from LDS, B-operand = weight frags.
template<int KDIM, int NDIM, bool L2EPI>
__global__ __launch_bounds__(256, 4) void k_gemm(const unsigned short* __restrict__ A,
                                                 const float* __restrict__ W,
                                                 const float* __restrict__ bias,
                                                 const int* __restrict__ hdr,
                                                 unsigned short* __restrict__ hout,
                                                 float* __restrict__ out) {
    int total = hdr[16];
    int row0 = blockIdx.y * 64;
    if (row0 >= total) return;
    int e = 0;
#pragma unroll
    for (int i = 1; i < NE; ++i)
        if (row0 >= hdr[8 + i]) e = i;

    int n0 = blockIdx.x * 64;
    const float* We = W + (size_t)e * NDIM * KDIM;
    const float* be = bias + (size_t)e * NDIM;

    constexpr int KC = 256;                       // K-chunk staged in LDS
    __shared__ __align__(16) unsigned short As[64 * KC];   // 32 KB

    int tid = threadIdx.x;
    int w = tid >> 6, lane = tid & 63;
    int fr = lane & 15, hi = lane >> 4;

    f32x4 acc[4];
#pragma unroll
    for (int m = 0; m < 4; ++m) acc[m] = f32x4{0.f, 0.f, 0.f, 0.f};

    // per-lane weight stream base: W row (n0 + w*16 + fr), k-offset hi*8
    const float* wp = We + (size_t)(n0 + w * 16 + fr) * KDIM + hi * 8;

    for (int kc = 0; kc < KDIM; kc += KC) {
        if (kc) __syncthreads();          // previous chunk's readers done
        // ---- stage token tile [64][KC] with XOR-swizzled 8-elem slots ----
#pragma unroll
        for (int j = 0; j < 8; ++j) {
            int c = j * 256 + tid;        // 16B chunk id in [0, 2048)
            int row = c >> 5;             // 32 slots per row
            int slot = c & 31;
            bf16x8 v = *(const bf16x8*)(A + (size_t)(row0 + row) * KDIM + kc + slot * 8);
            *(bf16x8*)&As[row * KC + (slot ^ (row & 7)) * 8] = v;
        }
        __syncthreads();
        // ---- barrier-free compute + weight streaming over this chunk ----
#pragma unroll
        for (int kk = 0; kk < KC; kk += 32) {
            f32x4 w0 = *(const f32x4*)(wp + kc + kk);
            f32x4 w1 = *(const f32x4*)(wp + kc + kk + 4);
            union { bf16x8 v; __hip_bfloat162 h2[4]; } bw;
            bw.h2[0] = __float22bfloat162_rn(make_float2(w0[0], w0[1]));
            bw.h2[1] = __float22bfloat162_rn(make_float2(w0[2], w0[3]));
            bw.h2[2] = __float22bfloat162_rn(make_float2(w1[0], w1[1]));
            bw.h2[3] = __float22bfloat162_rn(make_float2(w1[2], w1[3]));
            bf16x8 af[4];
#pragma unroll
            for (int m = 0; m < 4; ++m) {
                int row = m * 16 + fr;
                int slot = ((kk >> 3) + hi) ^ (row & 7);
                af[m] = *(const bf16x8*)&As[row * KC + slot * 8];
            }
#pragma unroll
            for (int m = 0; m < 4; ++m)
                acc[m] = __builtin_amdgcn_mfma_f32_16x16x32_bf16(af[m], bw.v, acc[m], 0, 0, 0);
        }
    }

    // ---- epilogue: C row = token (hi*4 + reg), col = n0 + w*16 + fr ----
    const int* perm = hdr + 64;
    int rbase = row0 + hi * 4;
    int cg = n0 + w * 16 + fr;
    float bvv = be[cg];
    if constexpr (!L2EPI) {
#pragma unroll
        for (int m = 0; m < 4; ++m) {
            int rg = rbase + m * 16;
#pragma unroll
            for (int r = 0; r < 4; ++r) {
                float v = acc[m][r] + bvv;
                v = v > 0.f ? v : 0.f;
                hout[(size_t)(rg + r) * NDIM + cg] = f2bf(v);
            }
        }
    } else {
#pragma unroll
        for (int m = 0; m < 4; ++m) {
            int rg = rbase + m * 16;
#pragma unroll
            for (int r = 0; r < 4; ++r) {
                int tk = perm[rg + r];
                if (tk < 0) continue;
                out[(size_t)tk * DD + cg] = acc[m][r] + bvv;
            }
        }
    }
}

extern "C" void kernel_launch(void* const* d_in, const int* in_sizes, int n_in,
                              void* d_out, int out_size, void* d_ws, size_t ws_size,
                              hipStream_t stream) {
    const float* x    = (const float*)d_in[0];
    const int*   orig = (const int*)d_in[1];
    const int*   hmap = (const int*)d_in[2];
    const float* W1   = (const float*)d_in[3];
    const float* b1   = (const float*)d_in[4];
    const float* W2   = (const float*)d_in[5];
    const float* b2   = (const float*)d_in[6];
    float* out = (float*)d_out;

    int* hdr = (int*)d_ws;
    unsigned short* xp   = (unsigned short*)((char*)d_ws + 16384);
    unsigned short* hbuf = (unsigned short*)((char*)d_ws + 16384 + (size_t)RP_CAP * DD * 2);

    k_route<<<1, 256, 0, stream>>>(orig, hmap, hdr);
    k_gather<<<RP_CAP, 256, 0, stream>>>(x, hdr, xp);
    // grid = (n-blocks, row-blocks); same-x blocks (shared weight panel) -> same XCD (idx%8 = x%8)
    k_gemm<DD, HH, false><<<dim3(HH / 64, RP_CAP / 64), 256, 0, stream>>>(xp, W1, b1, hdr, hbuf, nullptr);
    k_gemm<HH, DD, true><<<dim3(DD / 64, RP_CAP / 64), 256, 0, stream>>>(hbuf, W2, b2, hdr, nullptr, out);
}